// Round 1
// baseline (148.761 us; speedup 1.0000x reference)
//
#include <hip/hip_runtime.h>

// Workspace layout (float offsets). Needs ~390 KB of ws.
#define WS_FEAT   0        // [26][1960] CNN features per class (+pad)
#define WS_FC1P   51136    // [26][500]  fc1 partial (pre-relu, class part + bias)
#define WS_FC2T   64160    // [500][64]  fc2_w transposed
#define WS_AFLAT  96160    // [64][4]    A_B + A_C
#define WS_WX     96416    // [500][2]   fc1_w columns 1960,1961

// ---------------------------------------------------------------------------
// K1: per-class CNN (blocks 0..103: class c = bid>>2, quadrant q = bid&3)
//     + prep blocks 104 (fc2 transpose) and 105 (Aflat, Wx).
// Each conv block computes a 7x7 tile of the pooled conv2 output (all 10 oc)
// for one class, recomputing the conv1 halo locally.
// ---------------------------------------------------------------------------
__global__ __launch_bounds__(256) void k_cnn(
    const float* __restrict__ images,
    const float* __restrict__ c1w, const float* __restrict__ c1b,
    const float* __restrict__ c2w, const float* __restrict__ c2b,
    const float* __restrict__ fc2w, const float* __restrict__ fc1w,
    const float* __restrict__ A_B, const float* __restrict__ A_C,
    float* __restrict__ ws)
{
    const int bid = blockIdx.x;
    const int t = threadIdx.x;

    if (bid >= 104) {
        if (bid == 104) {
            float* fc2T = ws + WS_FC2T;
            for (int i = t; i < 32000; i += 256) {
                int e = i / 500, j = i - e * 500;
                fc2T[j * 64 + e] = fc2w[i];
            }
        } else {
            float* Af = ws + WS_AFLAT;
            if (t < 256) Af[t] = A_B[t] + A_C[t];
            float* Wx = ws + WS_WX;
            for (int i = t; i < 1000; i += 256) {
                int j = i >> 1, k = i & 1;
                Wx[i] = fc1w[j * 1962 + 1960 + k];
            }
        }
        return;
    }

    const int c  = bid >> 2, q = bid & 3;
    const int qy = q >> 1,  qx = q & 1;

    __shared__ float simg[1600];      // 40x40 image region
    __shared__ float sc1[5 * 324];    // [5][18][18] pooled conv1 region
    __shared__ float sw1[125];
    __shared__ float sb1[5];
    __shared__ float sw2[1250];
    __shared__ float sb2[10];

    // load 40x40 image region, origin (28*qy, 28*qx)
    {
        const float* ib = images + c * (68 * 68) + (28 * qy) * 68 + 28 * qx;
        for (int i = t; i < 800; i += 256) {
            int r = i / 20, c2 = i - r * 20;
            *(float2*)&simg[r * 40 + c2 * 2] = *(const float2*)&ib[r * 68 + c2 * 2];
        }
    }
    for (int i = t; i < 125; i += 256)  sw1[i] = c1w[i];
    if (t < 5)  sb1[t] = c1b[t];
    for (int i = t; i < 1250; i += 256) sw2[i] = c2w[i];
    if (t < 10) sb2[t] = c2b[t];
    __syncthreads();

    // conv1 + relu + pool2 -> sc1 [5][18][18] local region
    float b1r[5];
#pragma unroll
    for (int o = 0; o < 5; ++o) b1r[o] = sb1[o];

    for (int idx = t; idx < 324; idx += 256) {
        int ry = idx / 18, rx = idx - ry * 18;
        float ir[6][6];
#pragma unroll
        for (int a = 0; a < 6; ++a)
#pragma unroll
            for (int b2 = 0; b2 < 3; ++b2) {
                float2 v = *(const float2*)&simg[(2 * ry + a) * 40 + 2 * rx + 2 * b2];
                ir[a][2 * b2] = v.x; ir[a][2 * b2 + 1] = v.y;
            }
#pragma unroll
        for (int oc = 0; oc < 5; ++oc) {
            float a00 = b1r[oc], a01 = b1r[oc], a10 = b1r[oc], a11 = b1r[oc];
#pragma unroll
            for (int ky = 0; ky < 5; ++ky)
#pragma unroll
                for (int kx = 0; kx < 5; ++kx) {
                    float w = sw1[oc * 25 + ky * 5 + kx];
                    a00 += w * ir[ky][kx];
                    a01 += w * ir[ky][kx + 1];
                    a10 += w * ir[ky + 1][kx];
                    a11 += w * ir[ky + 1][kx + 1];
                }
            float v = fmaxf(fmaxf(fmaxf(a00, a01), fmaxf(a10, a11)), 0.f);
            sc1[oc * 324 + idx] = v;
        }
    }
    __syncthreads();

    // conv2 + relu + pool2 -> feat[c][oc][14][14] (this block: 7x7 tile)
    for (int idx = t; idx < 490; idx += 256) {
        int oc = idx / 49, pos = idx - oc * 49;
        int py = pos / 7,  px = pos - py * 7;
        float a00 = sb2[oc], a01 = a00, a10 = a00, a11 = a00;
#pragma unroll
        for (int ic = 0; ic < 5; ++ic) {
            float ir[6][6];
#pragma unroll
            for (int a = 0; a < 6; ++a)
#pragma unroll
                for (int b2 = 0; b2 < 3; ++b2) {
                    float2 v = *(const float2*)&sc1[ic * 324 + (2 * py + a) * 18 + 2 * px + 2 * b2];
                    ir[a][2 * b2] = v.x; ir[a][2 * b2 + 1] = v.y;
                }
#pragma unroll
            for (int ky = 0; ky < 5; ++ky)
#pragma unroll
                for (int kx = 0; kx < 5; ++kx) {
                    float w = sw2[oc * 125 + ic * 25 + ky * 5 + kx];
                    a00 += w * ir[ky][kx];
                    a01 += w * ir[ky][kx + 1];
                    a10 += w * ir[ky + 1][kx];
                    a11 += w * ir[ky + 1][kx + 1];
                }
        }
        float v = fmaxf(fmaxf(fmaxf(a00, a01), fmaxf(a10, a11)), 0.f);
        int gpy = qy * 7 + py, gpx = qx * 7 + px;
        ws[WS_FEAT + c * 1960 + oc * 196 + gpy * 14 + gpx] = v;
    }
}

// ---------------------------------------------------------------------------
// K2: fc1p[c][j] = fc1_b[j] + sum_k feat[c][k] * fc1_w[j][k]  (k < 1960)
// One j per wave (4 waves/block, 125 blocks). Weights register-resident.
// ---------------------------------------------------------------------------
__global__ __launch_bounds__(256) void k_fc1(
    const float* __restrict__ fc1w, const float* __restrict__ fc1b,
    float* __restrict__ ws)
{
    const int lane = threadIdx.x & 63;
    const int w    = threadIdx.x >> 6;
    const int j    = blockIdx.x * 4 + w;     // 0..499

    float wreg[31];
#pragma unroll
    for (int i = 0; i < 31; ++i) {
        int k = lane + 64 * i;
        wreg[i] = (k < 1960) ? fc1w[j * 1962 + k] : 0.f;
    }
    const float bj = fc1b[j];
    const float* feat = ws + WS_FEAT;
    float* fc1p = ws + WS_FC1P;

    for (int c = 0; c < 26; ++c) {
        const float* f = feat + c * 1960;
        float acc = 0.f;
#pragma unroll
        for (int i = 0; i < 31; ++i) acc += wreg[i] * f[lane + 64 * i]; // pad reads *0
#pragma unroll
        for (int off = 32; off >= 1; off >>= 1) acc += __shfl_xor(acc, off);
        if (lane == 0) fc1p[c * 500 + j] = acc + bj;
    }
}

// ---------------------------------------------------------------------------
// K3: per-sample: h = relu(fc1p[cls] + x.Wx) -> fc2 GEMV -> softmax (wave=64
// experts) -> s = (sum_e exp_e * A_e * diff) / sum_e exp_e.
// 8 samples per block, 1024 blocks.
// ---------------------------------------------------------------------------
__global__ __launch_bounds__(256) void k_moe(
    const float* __restrict__ x, const int* __restrict__ cls,
    const float* __restrict__ fc2b, const float* __restrict__ x_tar,
    const float* __restrict__ ws, float* __restrict__ out)
{
    __shared__ float sh[8][500];
    __shared__ float sred[2048];   // [p][s][e]
    const int t = threadIdx.x;
    const int b0 = blockIdx.x * 8;
    const float* fc1p = ws + WS_FC1P;
    const float* fc2T = ws + WS_FC2T;
    const float* Af   = ws + WS_AFLAT;
    const float* Wx   = ws + WS_WX;

    int cs[8]; float xs0[8], xs1[8];
#pragma unroll
    for (int s = 0; s < 8; ++s) {
        cs[s]  = cls[b0 + s];
        xs0[s] = x[2 * (b0 + s)];
        xs1[s] = x[2 * (b0 + s) + 1];
    }
    for (int j = t; j < 500; j += 256) {
        float2 wx = *(const float2*)&Wx[2 * j];
#pragma unroll
        for (int s = 0; s < 8; ++s) {
            float v = fc1p[cs[s] * 500 + j] + xs0[s] * wx.x + xs1[s] * wx.y;
            sh[s][j] = fmaxf(v, 0.f);
        }
    }
    __syncthreads();

    const int e = t & 63, p = t >> 6;
    float acc[8];
#pragma unroll
    for (int s = 0; s < 8; ++s) acc[s] = 0.f;

    const int jbeg = p * 128;
    const int jend = (p == 3) ? 500 : (jbeg + 128);
    for (int j4 = jbeg; j4 < jend; j4 += 4) {
        float w0 = fc2T[(j4 + 0) * 64 + e];
        float w1 = fc2T[(j4 + 1) * 64 + e];
        float w2 = fc2T[(j4 + 2) * 64 + e];
        float w3 = fc2T[(j4 + 3) * 64 + e];
#pragma unroll
        for (int s = 0; s < 8; ++s) {
            float4 h4 = *(const float4*)&sh[s][j4];
            acc[s] += h4.x * w0 + h4.y * w1 + h4.z * w2 + h4.w * w3;
        }
    }
#pragma unroll
    for (int s = 0; s < 8; ++s) sred[p * 512 + s * 64 + e] = acc[s];
    __syncthreads();

    const float xt0 = x_tar[0], xt1 = x_tar[1];
    const float be = fc2b[e];
    const float4 a4 = *(const float4*)&Af[4 * e];
#pragma unroll
    for (int half = 0; half < 2; ++half) {
        int s = half * 4 + p;   // each wave owns one sample here
        float logit = be + sred[s * 64 + e] + sred[512 + s * 64 + e]
                    + sred[1024 + s * 64 + e] + sred[1536 + s * 64 + e];
        float m = logit;
#pragma unroll
        for (int off = 32; off >= 1; off >>= 1) m = fmaxf(m, __shfl_xor(m, off));
        float ex = __expf(logit - m);
        float sum = ex;
        float m0 = ex * a4.x, m1 = ex * a4.y, m2 = ex * a4.z, m3 = ex * a4.w;
#pragma unroll
        for (int off = 32; off >= 1; off >>= 1) {
            sum += __shfl_xor(sum, off);
            m0 += __shfl_xor(m0, off);
            m1 += __shfl_xor(m1, off);
            m2 += __shfl_xor(m2, off);
            m3 += __shfl_xor(m3, off);
        }
        if (e == 0) {
            int b = b0 + s;
            float d0 = xt0 - x[2 * b], d1 = xt1 - x[2 * b + 1];
            float inv = 1.f / sum;
            out[2 * b]     = (m0 * d0 + m1 * d1) * inv;
            out[2 * b + 1] = (m2 * d0 + m3 * d1) * inv;
        }
    }
}

extern "C" void kernel_launch(void* const* d_in, const int* in_sizes, int n_in,
                              void* d_out, int out_size, void* d_ws, size_t ws_size,
                              hipStream_t stream) {
    const float* x      = (const float*)d_in[0];
    const int*   cls    = (const int*)  d_in[1];
    const float* images = (const float*)d_in[2];
    const float* c1w    = (const float*)d_in[3];
    const float* c1b    = (const float*)d_in[4];
    const float* c2w    = (const float*)d_in[5];
    const float* c2b    = (const float*)d_in[6];
    const float* fc1w   = (const float*)d_in[7];
    const float* fc1b   = (const float*)d_in[8];
    const float* fc2w   = (const float*)d_in[9];
    const float* fc2b   = (const float*)d_in[10];
    const float* A_B    = (const float*)d_in[11];
    const float* A_C    = (const float*)d_in[12];
    const float* x_tar  = (const float*)d_in[13];
    float* out = (float*)d_out;
    float* ws  = (float*)d_ws;

    k_cnn<<<106, 256, 0, stream>>>(images, c1w, c1b, c2w, c2b, fc2w, fc1w, A_B, A_C, ws);
    k_fc1<<<125, 256, 0, stream>>>(fc1w, fc1b, ws);
    k_moe<<<1024, 256, 0, stream>>>(x, cls, fc2b, x_tar, ws, out);
}

// Round 2
// 136.188 us; speedup vs baseline: 1.0923x; 1.0923x over previous
//
#include <hip/hip_runtime.h>

// Workspace layout (float offsets), ~930 KB total.
#define WS_SC1    0         // [26][5][32][32] pooled conv1
#define WS_FEAT   133120    // [26][1960]      pooled conv2 (flattened)
#define WS_FC1P   184080    // [26][500]       fc1 partial (class part + bias)
#define WS_FC2P   197080    // [125][64][4]    fc2 weights packed float4 by (j4,e)
#define WS_AFLAT  229080    // [64][4]         A_B + A_C
#define WS_WX     229336    // [500][2]        fc1_w columns 1960,1961

// ---------------------------------------------------------------------------
// K1a: conv1 + relu + pool2 for all classes.
// blocks 0..519: (class c, out-channel oc, row-group g). One pooled output
// per thread; image patch read through L1 (18 KB/class), weights in SGPRs.
// blocks 520,521: prep (fc2 float4 pack; Aflat/Wx/fc1p zero).
// ---------------------------------------------------------------------------
__global__ __launch_bounds__(256) void k_conv1(
    const float* __restrict__ images, const float* __restrict__ c1w,
    const float* __restrict__ c1b, const float* __restrict__ fc2w,
    const float* __restrict__ fc1w, const float* __restrict__ A_B,
    const float* __restrict__ A_C, float* __restrict__ ws)
{
    const int b = blockIdx.x, t = threadIdx.x;
    if (b >= 520) {
        if (b == 520) {
            // fc2P[(j4*64+e)*4 + q] = fc2w[e*500 + 4*j4 + q]
            float* P = ws + WS_FC2P;
            for (int i = t; i < 8000; i += 256) {   // i = j4*64 + e
                int j4 = i >> 6, e = i & 63;
                float4 v;
                v.x = fc2w[e * 500 + 4 * j4 + 0];
                v.y = fc2w[e * 500 + 4 * j4 + 1];
                v.z = fc2w[e * 500 + 4 * j4 + 2];
                v.w = fc2w[e * 500 + 4 * j4 + 3];
                *(float4*)&P[i * 4] = v;
            }
        } else {
            float* Af = ws + WS_AFLAT;
            if (t < 256) Af[t] = A_B[t] + A_C[t];
            float* Wx = ws + WS_WX;
            for (int i = t; i < 1000; i += 256) {
                int j = i >> 1, k = i & 1;
                Wx[i] = fc1w[j * 1962 + 1960 + k];
            }
            float* fp = ws + WS_FC1P;                // zero for k_fc1 atomics
            for (int i = t; i < 13000; i += 256) fp[i] = 0.f;
        }
        return;
    }

    const int c = b / 20, r = b - c * 20;
    const int oc = r >> 2, g = r & 3;
    const int py = g * 8 + (t >> 5), px = t & 31;   // pooled coords [32x32]

    float wr[25];                                    // block-uniform -> SGPRs
#pragma unroll
    for (int i = 0; i < 25; ++i) wr[i] = c1w[oc * 25 + i];
    const float bias = c1b[oc];

    const float* im = images + c * 4624 + (2 * py) * 68 + 2 * px;
    float ir[6][6];
#pragma unroll
    for (int a = 0; a < 6; ++a)
#pragma unroll
        for (int q = 0; q < 3; ++q) {
            float2 v = *(const float2*)&im[a * 68 + 2 * q];
            ir[a][2 * q] = v.x; ir[a][2 * q + 1] = v.y;
        }

    float a00 = bias, a01 = bias, a10 = bias, a11 = bias;
#pragma unroll
    for (int ky = 0; ky < 5; ++ky)
#pragma unroll
        for (int kx = 0; kx < 5; ++kx) {
            float w = wr[ky * 5 + kx];
            a00 += w * ir[ky][kx];     a01 += w * ir[ky][kx + 1];
            a10 += w * ir[ky + 1][kx]; a11 += w * ir[ky + 1][kx + 1];
        }
    float v = fmaxf(fmaxf(fmaxf(a00, a01), fmaxf(a10, a11)), 0.f);
    ws[WS_SC1 + ((c * 5 + oc) * 32 + py) * 32 + px] = v;
}

// ---------------------------------------------------------------------------
// K1b: conv2 + relu + pool2. 260 blocks = (class c, oc). Threads 0..195 each
// produce one pooled output; inputs via L1 (20 KB/class), weights via LDS
// broadcast (same-address = conflict-free).
// ---------------------------------------------------------------------------
__global__ __launch_bounds__(256) void k_conv2(
    const float* __restrict__ c2w, const float* __restrict__ c2b,
    float* __restrict__ ws)
{
    const int b = blockIdx.x, t = threadIdx.x;
    const int c = b / 10, oc = b - c * 10;

    __shared__ float sw[125];
    if (t < 125) sw[t] = c2w[oc * 125 + t];
    __syncthreads();
    if (t >= 196) return;

    const int py = t / 14, px = t - py * 14;
    const float bias = c2b[oc];
    float a00 = bias, a01 = bias, a10 = bias, a11 = bias;

    const float* base = ws + WS_SC1 + c * 5120 + (2 * py) * 32 + 2 * px;
#pragma unroll
    for (int ic = 0; ic < 5; ++ic) {
        const float* s1 = base + ic * 1024;
        float ir[6][6];
#pragma unroll
        for (int a = 0; a < 6; ++a)
#pragma unroll
            for (int q = 0; q < 3; ++q) {
                float2 v = *(const float2*)&s1[a * 32 + 2 * q];
                ir[a][2 * q] = v.x; ir[a][2 * q + 1] = v.y;
            }
#pragma unroll
        for (int ky = 0; ky < 5; ++ky)
#pragma unroll
            for (int kx = 0; kx < 5; ++kx) {
                float w = sw[ic * 25 + ky * 5 + kx];
                a00 += w * ir[ky][kx];     a01 += w * ir[ky][kx + 1];
                a10 += w * ir[ky + 1][kx]; a11 += w * ir[ky + 1][kx + 1];
            }
    }
    float v = fmaxf(fmaxf(fmaxf(a00, a01), fmaxf(a10, a11)), 0.f);
    ws[WS_FEAT + c * 1960 + oc * 196 + py * 14 + px] = v;
}

// ---------------------------------------------------------------------------
// K2: fc1p[c][j] += partial dot over half of K. 250 blocks x 4 waves
// (j per wave, K split in two 980-halves), atomicAdd combine.
// ---------------------------------------------------------------------------
__global__ __launch_bounds__(256) void k_fc1(
    const float* __restrict__ fc1w, const float* __restrict__ fc1b,
    float* __restrict__ ws)
{
    const int lane = threadIdx.x & 63, w = threadIdx.x >> 6;
    const int jg = blockIdx.x >> 1, half = blockIdx.x & 1;
    const int j = jg * 4 + w;
    const int kbase = half * 980;

    float wreg[16];
#pragma unroll
    for (int i = 0; i < 16; ++i) {
        int kl = lane + 64 * i;
        wreg[i] = (kl < 980) ? fc1w[j * 1962 + kbase + kl] : 0.f;
    }
    const float bj = (half == 0) ? fc1b[j] : 0.f;
    const float* feat = ws + WS_FEAT;
    float* fc1p = ws + WS_FC1P;

    for (int c = 0; c < 26; ++c) {
        const float* f = feat + c * 1960 + kbase;
        float acc0 = 0.f, acc1 = 0.f;
#pragma unroll
        for (int i = 0; i < 16; i += 2) {
            int k0 = lane + 64 * i, k1 = lane + 64 * (i + 1);
            acc0 += wreg[i]     * f[(k0 < 980) ? k0 : 0];
            acc1 += wreg[i + 1] * f[(k1 < 980) ? k1 : 0];
        }
        float acc = acc0 + acc1;
#pragma unroll
        for (int off = 32; off >= 1; off >>= 1) acc += __shfl_xor(acc, off);
        if (lane == 0) atomicAdd(&fc1p[c * 500 + j], acc + bj);
    }
}

// ---------------------------------------------------------------------------
// K3: per-sample h = relu(fc1p[cls] + x.Wx) -> fc2 GEMV (packed float4
// weights) -> wave softmax over 64 experts -> expert-weighted 2x2 combine.
// 8 samples/block, 1024 blocks.
// ---------------------------------------------------------------------------
__global__ __launch_bounds__(256) void k_moe(
    const float* __restrict__ x, const int* __restrict__ cls,
    const float* __restrict__ fc2b, const float* __restrict__ x_tar,
    const float* __restrict__ ws, float* __restrict__ out)
{
    __shared__ float sh[8][500];
    __shared__ float sred[2048];   // [p][s][e]
    const int t = threadIdx.x;
    const int b0 = blockIdx.x * 8;
    const float* fc1p = ws + WS_FC1P;
    const float* fc2P = ws + WS_FC2P;
    const float* Af   = ws + WS_AFLAT;
    const float* Wx   = ws + WS_WX;

    int cs[8]; float xs0[8], xs1[8];
#pragma unroll
    for (int s = 0; s < 8; ++s) {
        cs[s]  = cls[b0 + s];
        xs0[s] = x[2 * (b0 + s)];
        xs1[s] = x[2 * (b0 + s) + 1];
    }
    for (int j = t; j < 500; j += 256) {
        float2 wx = *(const float2*)&Wx[2 * j];
#pragma unroll
        for (int s = 0; s < 8; ++s) {
            float v = fc1p[cs[s] * 500 + j] + xs0[s] * wx.x + xs1[s] * wx.y;
            sh[s][j] = fmaxf(v, 0.f);
        }
    }
    __syncthreads();

    const int e = t & 63, p = t >> 6;
    float acc[8];
#pragma unroll
    for (int s = 0; s < 8; ++s) acc[s] = 0.f;

    const int gbeg = p * 32;
    const int gend = (p == 3) ? 125 : (gbeg + 32);
    for (int j4 = gbeg; j4 < gend; ++j4) {
        float4 wv = *(const float4*)&fc2P[(j4 * 64 + e) * 4];
#pragma unroll
        for (int s = 0; s < 8; ++s) {
            float4 h4 = *(const float4*)&sh[s][j4 * 4];
            acc[s] += h4.x * wv.x + h4.y * wv.y + h4.z * wv.z + h4.w * wv.w;
        }
    }
#pragma unroll
    for (int s = 0; s < 8; ++s) sred[p * 512 + s * 64 + e] = acc[s];
    __syncthreads();

    const float xt0 = x_tar[0], xt1 = x_tar[1];
    const float be = fc2b[e];
    const float4 a4 = *(const float4*)&Af[4 * e];
#pragma unroll
    for (int half = 0; half < 2; ++half) {
        int s = half * 4 + p;
        float logit = be + sred[s * 64 + e] + sred[512 + s * 64 + e]
                    + sred[1024 + s * 64 + e] + sred[1536 + s * 64 + e];
        float m = logit;
#pragma unroll
        for (int off = 32; off >= 1; off >>= 1) m = fmaxf(m, __shfl_xor(m, off));
        float ex = __expf(logit - m);
        float sum = ex;
        float m0 = ex * a4.x, m1 = ex * a4.y, m2 = ex * a4.z, m3 = ex * a4.w;
#pragma unroll
        for (int off = 32; off >= 1; off >>= 1) {
            sum += __shfl_xor(sum, off);
            m0 += __shfl_xor(m0, off);
            m1 += __shfl_xor(m1, off);
            m2 += __shfl_xor(m2, off);
            m3 += __shfl_xor(m3, off);
        }
        if (e == 0) {
            int b = b0 + s;
            float d0 = xt0 - x[2 * b], d1 = xt1 - x[2 * b + 1];
            float inv = 1.f / sum;
            out[2 * b]     = (m0 * d0 + m1 * d1) * inv;
            out[2 * b + 1] = (m2 * d0 + m3 * d1) * inv;
        }
    }
}

extern "C" void kernel_launch(void* const* d_in, const int* in_sizes, int n_in,
                              void* d_out, int out_size, void* d_ws, size_t ws_size,
                              hipStream_t stream) {
    const float* x      = (const float*)d_in[0];
    const int*   cls    = (const int*)  d_in[1];
    const float* images = (const float*)d_in[2];
    const float* c1w    = (const float*)d_in[3];
    const float* c1b    = (const float*)d_in[4];
    const float* c2w    = (const float*)d_in[5];
    const float* c2b    = (const float*)d_in[6];
    const float* fc1w   = (const float*)d_in[7];
    const float* fc1b   = (const float*)d_in[8];
    const float* fc2w   = (const float*)d_in[9];
    const float* fc2b   = (const float*)d_in[10];
    const float* A_B    = (const float*)d_in[11];
    const float* A_C    = (const float*)d_in[12];
    const float* x_tar  = (const float*)d_in[13];
    float* out = (float*)d_out;
    float* ws  = (float*)d_ws;

    k_conv1<<<522, 256, 0, stream>>>(images, c1w, c1b, fc2w, fc1w, A_B, A_C, ws);
    k_conv2<<<260, 256, 0, stream>>>(c2w, c2b, ws);
    k_fc1  <<<250, 256, 0, stream>>>(fc1w, fc1b, ws);
    k_moe  <<<1024, 256, 0, stream>>>(x, cls, fc2b, x_tar, ws, out);
}